// Round 8
// baseline (2108.046 us; speedup 1.0000x reference)
//
#include <hip/hip_runtime.h>
#include <hip/hip_bf16.h>

#define T_TOK 8192
#define HD 2048
#define ID 5632
#define NE 8

typedef __bf16 bf16x8 __attribute__((ext_vector_type(8)));
typedef float f32x4 __attribute__((ext_vector_type(4)));

// ---------------- exp LUT: lut[i] = int(exp((i-1024)/128) * 2^16), i in [0,1024] ----------------
__global__ void k_build_lut(int* __restrict__ lut) {
    int i = blockIdx.x * blockDim.x + threadIdx.x;
    if (i <= 1024) {
        float xv = (float)(i - 1024) * (1.0f / 128.0f);
        lut[i] = (int)(expf(xv) * 65536.0f);   // (int) truncates toward zero == astype(int32)
    }
}

// ---------------- Router: one wave per token, x-row cached in regs ----------------
__global__ __launch_bounds__(64)
void k_router(const float* __restrict__ x, const float* __restrict__ wg,
              const int* __restrict__ lut, int* __restrict__ counts,
              int* __restrict__ lists, float* __restrict__ wlist) {
    const int tok  = blockIdx.x;
    const int lane = threadIdx.x;
    const float* xr = x + (size_t)tok * HD;

    float xc[32];
    #pragma unroll
    for (int kk = 0; kk < 32; ++kk) xc[kk] = xr[lane + kk * 64];

    double dot[NE];
    #pragma unroll
    for (int e = 0; e < NE; ++e) {
        const float* wr = wg + e * HD;
        double acc = 0.0;
        #pragma unroll
        for (int kk = 0; kk < 32; ++kk)
            acc += (double)xc[kk] * (double)wr[lane + kk * 64];
        #pragma unroll
        for (int off = 32; off > 0; off >>= 1)
            acc += __shfl_down(acc, off);
        dot[e] = acc;   // valid on lane 0
    }
    if (lane == 0) {
        int li[NE];
        #pragma unroll
        for (int e = 0; e < NE; ++e)
            li[e] = (int)rintf((float)dot[e] * 128.0f);   // round-half-even == jnp.round
        int m = li[0];
        #pragma unroll
        for (int e = 1; e < NE; ++e) m = li[e] > m ? li[e] : m;
        int ev[NE]; int s = 0;
        #pragma unroll
        for (int e = 0; e < NE; ++e) {
            int sh = li[e] - m;
            if (sh < -1024) sh = -1024;
            ev[e] = lut[sh + 1024];
            s += ev[e];
        }
        int i0 = 0;
        #pragma unroll
        for (int e = 1; e < NE; ++e) if (ev[e] > ev[i0]) i0 = e;
        int i1 = -1;
        #pragma unroll
        for (int e = 0; e < NE; ++e) {
            if (e == i0) continue;
            if (i1 < 0 || ev[e] > ev[i1]) i1 = e;
        }
        float fs = (float)s;
        float r0 = (float)ev[i0] / fs;
        float r1 = (float)ev[i1] / fs;
        float ts = r0 + r1;
        float w0 = r0 / ts, w1 = r1 / ts;

        int p0 = atomicAdd(&counts[i0], 1);
        lists[i0 * T_TOK + p0] = (tok << 1);
        wlist[i0 * T_TOK + p0] = w0;
        int p1 = atomicAdd(&counts[i1], 1);
        lists[i1 * T_TOK + p1] = (tok << 1) | 1;
        wlist[i1 * T_TOK + p1] = w1;
    }
}

// ---------------- fp32 -> bf16 bulk conversion (memory-bound) ----------------
__device__ __forceinline__ bf16x8 cvt8(const float* __restrict__ s) {
    const f32x4 v0 = __builtin_nontemporal_load(reinterpret_cast<const f32x4*>(s));
    const f32x4 v1 = __builtin_nontemporal_load(reinterpret_cast<const f32x4*>(s + 4));
    bf16x8 h;
    h[0] = (__bf16)v0[0]; h[1] = (__bf16)v0[1]; h[2] = (__bf16)v0[2]; h[3] = (__bf16)v0[3];
    h[4] = (__bf16)v1[0]; h[5] = (__bf16)v1[1]; h[6] = (__bf16)v1[2]; h[7] = (__bf16)v1[3];
    return h;
}

__global__ __launch_bounds__(256)
void k_cvt_bf16(const float* __restrict__ src, __bf16* __restrict__ dst, long n8) {
    long i = (long)blockIdx.x * blockDim.x + threadIdx.x;
    const long stride = (long)gridDim.x * blockDim.x;
    for (; i < n8; i += stride)
        *reinterpret_cast<bf16x8*>(dst + i * 8) = cvt8(src + i * 8);
}

// one launch for the three weight tensors (equal sizes)
__global__ __launch_bounds__(256)
void k_cvt3_bf16(const float* __restrict__ s0, const float* __restrict__ s1, const float* __restrict__ s2,
                 __bf16* __restrict__ d0, __bf16* __restrict__ d1, __bf16* __restrict__ d2, long n8each) {
    long i = (long)blockIdx.x * blockDim.x + threadIdx.x;
    const long stride = (long)gridDim.x * blockDim.x;
    const long n2 = 2 * n8each, n3 = 3 * n8each;
    for (; i < n3; i += stride) {
        const float* src; __bf16* dst; long off;
        if (i < n8each)      { src = s0; dst = d0; off = i; }
        else if (i < n2)     { src = s1; dst = d1; off = i - n8each; }
        else                 { src = s2; dst = d2; off = i - n2; }
        *reinterpret_cast<bf16x8*>(dst + off * 8) = cvt8(src + off * 8);
    }
}

// ---------------- helpers ----------------
__device__ __forceinline__ void cvt_store8(void* lds_base, int woff, const float* __restrict__ src) {
    const f32x4 v0 = *reinterpret_cast<const f32x4*>(src);
    const f32x4 v1 = *reinterpret_cast<const f32x4*>(src + 4);
    bf16x8 h;
    h[0] = (__bf16)v0[0]; h[1] = (__bf16)v0[1]; h[2] = (__bf16)v0[2]; h[3] = (__bf16)v0[3];
    h[4] = (__bf16)v1[0]; h[5] = (__bf16)v1[1]; h[6] = (__bf16)v1[2]; h[7] = (__bf16)v1[3];
    *reinterpret_cast<bf16x8*>(reinterpret_cast<char*>(lds_base) + woff) = h;
}

__device__ __forceinline__ bf16x8 lds_frag(const void* lds_base, int row, int klo) {
    int off = (row * 128 + klo) ^ ((row & 7) << 4);
    return *reinterpret_cast<const bf16x8*>(reinterpret_cast<const char*>(lds_base) + off);
}

// async 16B global->LDS; LDS dest is wave-uniform base + lane*16 (m104)
__device__ __forceinline__ void gload16(const void* g, void* l) {
    __builtin_amdgcn_global_load_lds(
        (const __attribute__((address_space(1))) unsigned int*)g,
        (__attribute__((address_space(3))) unsigned int*)l,
        16, 0, 0);
}

// ---- fragment sets (register double-buffer across kk phases) ----
struct FragsA { bf16x8 a[4]; bf16x8 b1[2]; bf16x8 b3[2]; };
struct FragsB { bf16x8 a[4]; bf16x8 b[2]; };

__device__ __forceinline__ void read_fragsA(FragsA& f, const __bf16* bx, const __bf16* w1s, const __bf16* w3s,
                                            int wm, int wn, int lane, int klo) {
    #pragma unroll
    for (int m = 0; m < 4; ++m)
        f.a[m] = lds_frag(bx, wm + m * 16 + (lane & 15), klo);
    #pragma unroll
    for (int n = 0; n < 2; ++n) {
        const int r = wn + n * 16 + (lane & 15);
        f.b1[n] = lds_frag(w1s, r, klo);
        f.b3[n] = lds_frag(w3s, r, klo);
    }
}

__device__ __forceinline__ void mfmaA(f32x4 (&accg)[4][2], f32x4 (&accu)[4][2], const FragsA& f) {
    __builtin_amdgcn_s_setprio(1);
    #pragma unroll
    for (int m = 0; m < 4; ++m)
        #pragma unroll
        for (int n = 0; n < 2; ++n) {
            accg[m][n] = __builtin_amdgcn_mfma_f32_16x16x32_bf16(f.a[m], f.b1[n], accg[m][n], 0, 0, 0);
            accu[m][n] = __builtin_amdgcn_mfma_f32_16x16x32_bf16(f.a[m], f.b3[n], accu[m][n], 0, 0, 0);
        }
    __builtin_amdgcn_s_setprio(0);
}

__device__ __forceinline__ void read_fragsB(FragsB& f, const __bf16* bh, const __bf16* bw,
                                            int wm, int wn, int lane, int klo) {
    #pragma unroll
    for (int m = 0; m < 4; ++m)
        f.a[m] = lds_frag(bh, wm + m * 16 + (lane & 15), klo);
    #pragma unroll
    for (int n = 0; n < 2; ++n)
        f.b[n] = lds_frag(bw, wn + n * 16 + (lane & 15), klo);
}

__device__ __forceinline__ void mfmaB(f32x4 (&acc)[4][2], const FragsB& f) {
    __builtin_amdgcn_s_setprio(1);
    #pragma unroll
    for (int m = 0; m < 4; ++m)
        #pragma unroll
        for (int n = 0; n < 2; ++n)
            acc[m][n] = __builtin_amdgcn_mfma_f32_16x16x32_bf16(f.a[m], f.b[n], acc[m][n], 0, 0, 0);
    __builtin_amdgcn_s_setprio(0);
}

// ================= FAST PATH (bf16 sources, reg-pipelined K-step) =================

// Pass A: h = silu(x@w1^T) * (x@w3^T). 512 thr, tile 128x128, BK=64, 3-buf LDS (144KB).
// Schedule per iter: [read kk1(t) | STAGE(t+2)] MFMA kk0(t) | vmcnt(6)+bar | read kk0(t+1) | MFMA kk1(t)
__global__ __launch_bounds__(512, 2)
void k_gateup_b16(const __bf16* __restrict__ xb, const __bf16* __restrict__ w1b,
                  const __bf16* __restrict__ w3b,
                  const int* __restrict__ counts, const int* __restrict__ lists,
                  __bf16* __restrict__ hbuf) {
    const int e   = blockIdx.z;
    const int cnt = counts[e];
    const int mt  = blockIdx.y;
    if (mt * 128 >= cnt) return;
    const int nt  = blockIdx.x;

    __shared__ __align__(16) __bf16 sX [3][8192];
    __shared__ __align__(16) __bf16 sW1[3][8192];
    __shared__ __align__(16) __bf16 sW3[3][8192];

    const int t    = threadIdx.x;
    const int lane = t & 63;
    const int wave = t >> 6;             // 0..7
    const int wm   = (wave >> 2) * 64;   // 0,64
    const int wn   = (wave & 3) * 32;    // 0,32,64,96

    // staging: tile 16KB = 16 chunks of 1024B; wave owns chunks w and w+8.
    // chunk c covers rows 8c..8c+7; lane l -> row 8c+(l>>3), k-granule ((l&7)^(l>>3))*8
    // == inverse of read swizzle byte ^= ((row&7)<<4).
    const int lrow = lane >> 3;
    const int kel  = ((lane & 7) ^ lrow) * 8;

    const __bf16* gX[2]; const __bf16* g1[2]; const __bf16* g3[2];
    int ldo[2];
    #pragma unroll
    for (int cq = 0; cq < 2; ++cq) {
        const int c   = wave + cq * 8;
        const int row = c * 8 + lrow;
        int mi  = mt * 128 + row;
        int mic = mi < cnt - 1 ? mi : cnt - 1;
        int tok = lists[e * T_TOK + mic] >> 1;
        gX[cq] = xb + (size_t)tok * HD + kel;
        const int grow = nt * 128 + row;
        g1[cq] = w1b + ((size_t)e * ID + grow) * HD + kel;
        g3[cq] = w3b + ((size_t)e * ID + grow) * HD + kel;
        ldo[cq] = c * 1024;
    }

    f32x4 accg[4][2] = {};
    f32x4 accu[4][2] = {};

#define STAGE_A(b, kt) do { \
    _Pragma("unroll") \
    for (int cq = 0; cq < 2; ++cq) { \
        gload16(gX[cq] + (kt), (char*)sX [b] + ldo[cq]); \
        gload16(g1[cq] + (kt), (char*)sW1[b] + ldo[cq]); \
        gload16(g3[cq] + (kt), (char*)sW3[b] + ldo[cq]); \
    } } while (0)

    const int klo0 = (lane >> 4) << 4;   // byte offset of lane's 8-bf16 chunk, kk=0
    const int klo1 = 64 + klo0;          // kk=1

    const int NT = HD / 64;   // 32
    STAGE_A(0, 0);
    STAGE_A(1, 64);
    asm volatile("s_waitcnt vmcnt(6)" ::: "memory");   // tile0 landed; tile1 in flight
    __builtin_amdgcn_s_barrier();
    __builtin_amdgcn_sched_barrier(0);

    FragsA fc, fn;
    read_fragsA(fc, sX[0], sW1[0], sW3[0], wm, wn, lane, klo0);

    for (int it = 0; it < NT - 2; ++it) {
        const int bc = it % 3, bn2 = (it + 1) % 3, bs = (it + 2) % 3;
        read_fragsA(fn, sX[bc], sW1[bc], sW3[bc], wm, wn, lane, klo1);  // kk1(t), hides under MFMA kk0
        STAGE_A(bs, (it + 2) * 64);
        mfmaA(accg, accu, fc);                                          // kk0(t)
        asm volatile("s_waitcnt vmcnt(6)" ::: "memory");                // tile t+1 landed; t+2 in flight
        __builtin_amdgcn_s_barrier();
        __builtin_amdgcn_sched_barrier(0);
        read_fragsA(fc, sX[bn2], sW1[bn2], sW3[bn2], wm, wn, lane, klo0); // kk0(t+1), hides under MFMA kk1
        mfmaA(accg, accu, fn);                                          // kk1(t)
    }
    {   // it = NT-2: no new STAGE; drain tile NT-1
        const int bc = (NT - 2) % 3, bn2 = (NT - 1) % 3;
        read_fragsA(fn, sX[bc], sW1[bc], sW3[bc], wm, wn, lane, klo1);
        mfmaA(accg, accu, fc);
        asm volatile("s_waitcnt vmcnt(0)" ::: "memory");
        __builtin_amdgcn_s_barrier();
        __builtin_amdgcn_sched_barrier(0);
        read_fragsA(fc, sX[bn2], sW1[bn2], sW3[bn2], wm, wn, lane, klo0);
        mfmaA(accg, accu, fn);
    }
    {   // it = NT-1
        const int bc = (NT - 1) % 3;
        read_fragsA(fn, sX[bc], sW1[bc], sW3[bc], wm, wn, lane, klo1);
        mfmaA(accg, accu, fc);
        mfmaA(accg, accu, fn);
    }
#undef STAGE_A

    // SwiGLU epilogue -> hbuf[slot][i] (bf16). Nontemporal: hbuf (184MB stream) must not
    // evict the per-expert weight panels from L2/L3 (re-read across mt-groups).
    const int col_l = lane & 15;
    const int row_l = (lane >> 4) * 4;
    #pragma unroll
    for (int m = 0; m < 4; ++m) {
        #pragma unroll
        for (int j = 0; j < 4; ++j) {
            int tl = wm + m * 16 + row_l + j;
            int mi = mt * 128 + tl;
            if (mi < cnt) {
                int slot = lists[e * T_TOK + mi];
                __bf16* hrow = hbuf + (size_t)slot * ID + nt * 128 + wn;
                #pragma unroll
                for (int n = 0; n < 2; ++n) {
                    float g = accg[m][n][j];
                    float u = accu[m][n][j];
                    float hv = (g / (1.0f + expf(-g))) * u;
                    __builtin_nontemporal_store((__bf16)hv, &hrow[n * 16 + col_l]);
                }
            }
        }
    }
}

// Pass B: out[tok] += w * (h @ w2^T). 512 thr, tile 128x128, BK=64, 3-buf LDS (96KB).
__global__ __launch_bounds__(512, 2)
void k_down_b16(const __bf16* __restrict__ hbuf, const __bf16* __restrict__ w2b,
                const int* __restrict__ counts, const int* __restrict__ lists,
                const float* __restrict__ wlist, float* __restrict__ out) {
    const int e   = blockIdx.z;
    const int cnt = counts[e];
    const int mt  = blockIdx.y;
    if (mt * 128 >= cnt) return;
    const int nt  = blockIdx.x;

    __shared__ __align__(16) __bf16 sH[3][8192];
    __shared__ __align__(16) __bf16 sW[3][8192];

    const int t    = threadIdx.x;
    const int lane = t & 63;
    const int wave = t >> 6;
    const int wm   = (wave >> 2) * 64;
    const int wn   = (wave & 3) * 32;

    const int lrow = lane >> 3;
    const int kel  = ((lane & 7) ^ lrow) * 8;

    const __bf16* gH[2]; const __bf16* gW[2];
    int ldo[2];
    #pragma unroll
    for (int cq = 0; cq < 2; ++cq) {
        const int c   = wave + cq * 8;
        const int row = c * 8 + lrow;
        int mi  = mt * 128 + row;
        int mic = mi < cnt - 1 ? mi : cnt - 1;
        int slot = lists[e * T_TOK + mic];
        gH[cq] = hbuf + (size_t)slot * ID + kel;
        const int grow = nt * 128 + row;
        gW[cq] = w2b + ((size_t)e * HD + grow) * ID + kel;
        ldo[cq] = c * 1024;
    }

    f32x4 acc[4][2] = {};

#define STAGE_B(b, kt) do { \
    _Pragma("unroll") \
    for (int cq = 0; cq < 2; ++cq) { \
        gload16(gH[cq] + (kt), (char*)sH[b] + ldo[cq]); \
        gload16(gW[cq] + (kt), (char*)sW[b] + ldo[cq]); \
    } } while (0)

    const int klo0 = (lane >> 4) << 4;
    const int klo1 = 64 + klo0;

    const int NT = ID / 64;   // 88
    STAGE_B(0, 0);
    STAGE_B(1, 64);
    asm volatile("s_waitcnt vmcnt(4)" ::: "memory");
    __builtin_amdgcn_s_barrier();
    __builtin_amdgcn_sched_barrier(0);

    FragsB fc, fn;
    read_fragsB(fc, sH[0], sW[0], wm, wn, lane, klo0);

    for (int it = 0; it < NT - 2; ++it) {
        const int bc = it % 3, bn2 = (it + 1) % 3, bs = (it + 2) % 3;
        read_fragsB(fn, sH[bc], sW[bc], wm, wn, lane, klo1);
        STAGE_B(bs, (it + 2) * 64);
        mfmaB(acc, fc);
        asm volatile("s_waitcnt vmcnt(4)" ::: "memory");
        __builtin_amdgcn_s_barrier();
        __builtin_amdgcn_sched_barrier(0);
        read_fragsB(fc, sH[bn2], sW[bn2], wm, wn, lane, klo0);
        mfmaB(acc, fn);
    }
    {   // it = NT-2
        const int bc = (NT - 2) % 3, bn2 = (NT - 1) % 3;
        read_fragsB(fn, sH[bc], sW[bc], wm, wn, lane, klo1);
        mfmaB(acc, fc);
        asm volatile("s_waitcnt vmcnt(0)" ::: "memory");
        __builtin_amdgcn_s_barrier();
        __builtin_amdgcn_sched_barrier(0);
        read_fragsB(fc, sH[bn2], sW[bn2], wm, wn, lane, klo0);
        mfmaB(acc, fn);
    }
    {   // it = NT-1
        const int bc = (NT - 1) % 3;
        read_fragsB(fn, sH[bc], sW[bc], wm, wn, lane, klo1);
        mfmaB(acc, fc);
        mfmaB(acc, fn);
    }
#undef STAGE_B

    // weighted scatter-add: exactly 2 atomic contributions per out element
    const int col_l = lane & 15;
    const int row_l = (lane >> 4) * 4;
    #pragma unroll
    for (int m = 0; m < 4; ++m) {
        #pragma unroll
        for (int j = 0; j < 4; ++j) {
            int tl = wm + m * 16 + row_l + j;
            int mi = mt * 128 + tl;
            if (mi < cnt) {
                int slot = lists[e * T_TOK + mi];
                int tok  = slot >> 1;
                float w  = wlist[e * T_TOK + mi];
                float* orow = out + (size_t)tok * HD + nt * 128 + wn;
                #pragma unroll
                for (int n = 0; n < 2; ++n)
                    atomicAdd(&orow[n * 16 + col_l], w * acc[m][n][j]);
            }
        }
    }
}

// ================= FALLBACK PATH (fp32 sources, reg-staged; round-1 proven) =================

__global__ __launch_bounds__(256)
void k_gateup_f32(const float* __restrict__ x, const float* __restrict__ w1,
                  const float* __restrict__ w3,
                  const int* __restrict__ counts, const int* __restrict__ lists,
                  __bf16* __restrict__ hbuf) {
    const int e   = blockIdx.z;
    const int cnt = counts[e];
    const int mt  = blockIdx.y;
    if (mt * 128 >= cnt) return;
    const int nt  = blockIdx.x;

    __shared__ __align__(16) __bf16 sX [128 * 64];
    __shared__ __align__(16) __bf16 sW1[128 * 64];
    __shared__ __align__(16) __bf16 sW3[128 * 64];

    const int t    = threadIdx.x;
    const int lane = t & 63;
    const int wave = t >> 6;
    const int wm   = (wave >> 1) * 64;
    const int wn   = (wave & 1) * 64;
    const int cc = t & 7;
    const int r0 = t >> 3;

    const float* srcX[4]; const float* src1[4]; const float* src3[4];
    int woff[4];
    #pragma unroll
    for (int q = 0; q < 4; ++q) {
        int row = r0 + 32 * q;
        int mi  = mt * 128 + row;
        int mic = mi < cnt - 1 ? mi : cnt - 1;
        int slot = lists[e * T_TOK + mic];
        int tok  = slot >> 1;
        srcX[q] = x + (size_t)tok * HD + cc * 8;
        int grow = nt * 128 + row;
        src1[q] = w1 + ((size_t)e * ID + grow) * HD + cc * 8;
        src3[q] = w3 + ((size_t)e * ID + grow) * HD + cc * 8;
        woff[q] = (row * 128 + cc * 16) ^ ((row & 7) << 4);
    }

    f32x4 accg[4][4] = {};
    f32x4 accu[4][4] = {};

    for (int kt = 0; kt < HD; kt += 64) {
        __syncthreads();
        #pragma unroll
        for (int q = 0; q < 4; ++q) {
            cvt_store8(sX,  woff[q], srcX[q] + kt);
            cvt_store8(sW1, woff[q], src1[q] + kt);
            cvt_store8(sW3, woff[q], src3[q] + kt);
        }
        __syncthreads();
        #pragma unroll
        for (int kk = 0; kk < 2; ++kk) {
            const int klo = kk * 64 + ((lane >> 4) << 4);
            bf16x8 af[4], b1f[4], b3f[4];
            #pragma unroll
            for (int m = 0; m < 4; ++m)
                af[m] = lds_frag(sX, wm + m * 16 + (lane & 15), klo);
            #pragma unroll
            for (int n = 0; n < 4; ++n) {
                int row = wn + n * 16 + (lane & 15);
                b1f[n] = lds_frag(sW1, row, klo);
                b3f[n] = lds_frag(sW3, row, klo);
            }
            #pragma unroll
            for (int m = 0; m < 4; ++m)
                #pragma unroll
                for (int n = 0; n < 4; ++n) {
                    accg[m][n] = __builtin_amdgcn_mfma_f32_16x16x32_bf16(af[m], b1f[n], accg[m][n], 0, 0, 0);
                    accu[m][n] = __builtin_amdgcn_mfma_f32_16x16x32_bf16(af[m], b3f[n], accu[m][n], 0, 0, 0);
                }
        }
    }

    const int col_l = lane & 15;
    const int row_l = (lane >> 4) * 4;
    #pragma unroll
    for (int m = 0; m < 4; ++m) {
        #pragma unroll
        for (int j = 0; j < 4; ++j) {
            int tl = wm + m * 16 + row_l + j;
            int mi = mt * 128 + tl;
            if (mi < cnt) {
                int slot = lists[e * T_TOK + mi];
                __bf16* hrow = hbuf + (size_t)slot * ID + nt * 128 + wn;
                #pragma unroll
                for (int n = 0; n < 4; ++n) {
                    float g = accg[m][n][j];
                    float u = accu[m][n][j];
                    float hv = (g / (1.0f + expf(-g))) * u;
                    hrow[n * 16 + col_l] = (__bf16)hv;
                }
            }
        }
    }
}

__global__ __launch_bounds__(256)
void k_down_f32(const __bf16* __restrict__ hbuf, const float* __restrict__ w2,
                const int* __restrict__ counts, const int* __restrict__ lists,
                const float* __restrict__ wlist, float* __restrict__ out) {
    const int e   = blockIdx.z;
    const int cnt = counts[e];
    const int mt  = blockIdx.y;
    if (mt * 128 >= cnt) return;
    const int nt  = blockIdx.x;

    __shared__ __align__(16) __bf16 sH[128 * 64];
    __shared__ __align__(16) __bf16 sW[128 * 64];

    const int t    = threadIdx.x;
    const int lane = t & 63;
    const int wave = t >> 6;
    const int wm   = (wave >> 1) * 64;
    const int wn   = (wave & 1) * 64;
    const int cc = t & 7;
    const int r0 = t >> 3;

    const __bf16* srcH[4]; const float* srcW[4];
    int woff[4];
    #pragma unroll
    for (int q = 0; q < 4; ++q) {
        int row = r0 + 32 * q;
        int mi  = mt * 128 + row;
        int mic = mi < cnt - 1 ? mi : cnt - 1;
        int slot = lists[e * T_TOK + mic];
        srcH[q] = hbuf + (size_t)slot * ID + cc * 8;
        int grow = nt * 128 + row;
        srcW[q] = w2 + ((size_t)e * HD + grow) * ID + cc * 8;
        woff[q] = (row * 128 + cc * 16) ^ ((row & 7) << 4);
    }

    f32x4 acc[4][4] = {};

    for (int kt = 0; kt < ID; kt += 64) {
        __syncthreads();
        #pragma unroll
        for (int q = 0; q < 4; ++q) {
            bf16x8 v = *reinterpret_cast<const bf16x8*>(srcH[q] + kt);
            *reinterpret_cast<bf16x8*>(reinterpret_cast<char*>(sH) + woff[q]) = v;
            cvt_store8(sW, woff[q], srcW[q] + kt);
        }
        __syncthreads();
        #pragma unroll
        for (int kk = 0; kk < 2; ++kk) {
            const int klo = kk * 64 + ((lane >> 4) << 4);
            bf16x8 af[4], bf[4];
            #pragma unroll
            for (int m = 0; m < 4; ++m)
                af[m] = lds_frag(sH, wm + m * 16 + (lane & 15), klo);
            #pragma unroll
            for (int n = 0; n < 4; ++n)
                bf[n] = lds_frag(sW, wn + n * 16 + (lane & 15), klo);
            #pragma unroll
            for (int m = 0; m < 4; ++m)
                #pragma unroll
                for (int n = 0; n < 4; ++n)
                    acc[m][n] = __builtin_amdgcn_mfma_f32_16x16x32_bf16(af[m], bf[n], acc[m][n], 0, 0, 0);
        }
    }

    const int col_l = lane & 15;
    const int row_l = (lane >> 4) * 4;
    #pragma unroll
    for (int m = 0; m < 4; ++m) {
        #pragma unroll
        for (int j = 0; j < 4; ++j) {
            int tl = wm + m * 16 + row_l + j;
            int mi = mt * 128 + tl;
            if (mi < cnt) {
                int slot = lists[e * T_TOK + mi];
                int tok  = slot >> 1;
                float w  = wlist[e * T_TOK + mi];
                float* orow = out + (size_t)tok * HD + nt * 128 + wn;
                #pragma unroll
                for (int n = 0; n < 4; ++n)
                    atomicAdd(&orow[n * 16 + col_l], w * acc[m][n][j]);
            }
        }
    }
}

extern "C" void kernel_launch(void* const* d_in, const int* in_sizes, int n_in,
                              void* d_out, int out_size, void* d_ws, size_t ws_size,
                              hipStream_t stream) {
    const float* x  = (const float*)d_in[0];
    const float* wg = (const float*)d_in[1];
    const float* w1 = (const float*)d_in[2];
    const float* w2 = (const float*)d_in[3];
    const float* w3 = (const float*)d_in[4];
    float* out = (float*)d_out;

    const size_t HBUF_B = (size_t)2 * T_TOK * ID * 2;      // 184,549,376
    const size_t XB_B   = (size_t)T_TOK * HD * 2;          //  33,554,432
    const size_t WB_B   = (size_t)NE * ID * HD * 2;        // 184,549,376 each
    const size_t SMALL  = 4608 + 512 + (size_t)NE * T_TOK * 4 * 2 + 4096;

    char* ws = (char*)d_ws;
    __bf16* hbuf = (__bf16*)ws;

    const size_t XB_OFF  = HBUF_B;
    const size_t W1_OFF  = XB_OFF + XB_B;
    const size_t W3_OFF  = W1_OFF + WB_B;
    const size_t W2_OFF  = W3_OFF + WB_B;
    const size_t TAIL    = W2_OFF + WB_B;
    const size_t NEED_FULL = TAIL + SMALL;
    const size_t NEED_MIN  = HBUF_B + SMALL;

    if (ws_size >= NEED_FULL) {
        __bf16* xb  = (__bf16*)(ws + XB_OFF);
        __bf16* w1b = (__bf16*)(ws + W1_OFF);
        __bf16* w3b = (__bf16*)(ws + W3_OFF);
        __bf16* w2b = (__bf16*)(ws + W2_OFF);
        int*   lut    = (int*)(ws + TAIL);
        int*   counts = (int*)(ws + TAIL + 4608);
        int*   lists  = (int*)(ws + TAIL + 4608 + 512);
        float* wlist  = (float*)(ws + TAIL + 4608 + 512 + (size_t)NE * T_TOK * 4);

        (void)hipMemsetAsync(out, 0, (size_t)out_size * sizeof(float), stream);
        (void)hipMemsetAsync(counts, 0, 64, stream);
        k_build_lut<<<dim3(5), dim3(256), 0, stream>>>(lut);
        k_router<<<dim3(T_TOK), dim3(64), 0, stream>>>(x, wg, lut, counts, lists, wlist);
        k_cvt_bf16<<<dim3(1024), dim3(256), 0, stream>>>(x, xb, (long)T_TOK * HD / 8);
        k_cvt3_bf16<<<dim3(4096), dim3(256), 0, stream>>>(w1, w3, w2, w1b, w3b, w2b, (long)NE * ID * HD / 8);
        k_gateup_b16<<<dim3(ID / 128, T_TOK / 128, NE), dim3(512), 0, stream>>>(xb, w1b, w3b, counts, lists, hbuf);
        k_down_b16<<<dim3(HD / 128, T_TOK / 128, NE), dim3(512), 0, stream>>>(hbuf, w2b, counts, lists, wlist, out);
    } else if (ws_size >= NEED_MIN) {
        int*   lut    = (int*)(ws + HBUF_B);
        int*   counts = (int*)(ws + HBUF_B + 4608);
        int*   lists  = (int*)(ws + HBUF_B + 4608 + 512);
        float* wlist  = (float*)(ws + HBUF_B + 4608 + 512 + (size_t)NE * T_TOK * 4);

        (void)hipMemsetAsync(out, 0, (size_t)out_size * sizeof(float), stream);
        (void)hipMemsetAsync(counts, 0, 64, stream);
        k_build_lut<<<dim3(5), dim3(256), 0, stream>>>(lut);
        k_router<<<dim3(T_TOK), dim3(64), 0, stream>>>(x, wg, lut, counts, lists, wlist);
        k_gateup_f32<<<dim3(ID / 128, T_TOK / 128, NE), dim3(256), 0, stream>>>(x, w1, w3, counts, lists, hbuf);
        k_down_f32<<<dim3(HD / 128, T_TOK / 128, NE), dim3(256), 0, stream>>>(hbuf, w2, counts, lists, wlist, out);
    } else {
        (void)hipMemsetAsync(d_out, 0x7F, (size_t)out_size * sizeof(float), stream);
    }
}

// Round 9
// 1997.384 us; speedup vs baseline: 1.0554x; 1.0554x over previous
//
#include <hip/hip_runtime.h>
#include <hip/hip_bf16.h>

#define T_TOK 8192
#define HD 2048
#define ID 5632
#define NE 8

typedef __bf16 bf16x8 __attribute__((ext_vector_type(8)));
typedef float f32x4 __attribute__((ext_vector_type(4)));

// ---------------- exp LUT: lut[i] = int(exp((i-1024)/128) * 2^16), i in [0,1024] ----------------
__global__ void k_build_lut(int* __restrict__ lut) {
    int i = blockIdx.x * blockDim.x + threadIdx.x;
    if (i <= 1024) {
        float xv = (float)(i - 1024) * (1.0f / 128.0f);
        lut[i] = (int)(expf(xv) * 65536.0f);   // (int) truncates toward zero == astype(int32)
    }
}

// ---------------- Router: one wave per token, x-row cached in regs ----------------
__global__ __launch_bounds__(64)
void k_router(const float* __restrict__ x, const float* __restrict__ wg,
              const int* __restrict__ lut, int* __restrict__ counts,
              int* __restrict__ lists, float* __restrict__ wlist) {
    const int tok  = blockIdx.x;
    const int lane = threadIdx.x;
    const float* xr = x + (size_t)tok * HD;

    float xc[32];
    #pragma unroll
    for (int kk = 0; kk < 32; ++kk) xc[kk] = xr[lane + kk * 64];

    double dot[NE];
    #pragma unroll
    for (int e = 0; e < NE; ++e) {
        const float* wr = wg + e * HD;
        double acc = 0.0;
        #pragma unroll
        for (int kk = 0; kk < 32; ++kk)
            acc += (double)xc[kk] * (double)wr[lane + kk * 64];
        #pragma unroll
        for (int off = 32; off > 0; off >>= 1)
            acc += __shfl_down(acc, off);
        dot[e] = acc;   // valid on lane 0
    }
    if (lane == 0) {
        int li[NE];
        #pragma unroll
        for (int e = 0; e < NE; ++e)
            li[e] = (int)rintf((float)dot[e] * 128.0f);   // round-half-even == jnp.round
        int m = li[0];
        #pragma unroll
        for (int e = 1; e < NE; ++e) m = li[e] > m ? li[e] : m;
        int ev[NE]; int s = 0;
        #pragma unroll
        for (int e = 0; e < NE; ++e) {
            int sh = li[e] - m;
            if (sh < -1024) sh = -1024;
            ev[e] = lut[sh + 1024];
            s += ev[e];
        }
        int i0 = 0;
        #pragma unroll
        for (int e = 1; e < NE; ++e) if (ev[e] > ev[i0]) i0 = e;
        int i1 = -1;
        #pragma unroll
        for (int e = 0; e < NE; ++e) {
            if (e == i0) continue;
            if (i1 < 0 || ev[e] > ev[i1]) i1 = e;
        }
        float fs = (float)s;
        float r0 = (float)ev[i0] / fs;
        float r1 = (float)ev[i1] / fs;
        float ts = r0 + r1;
        float w0 = r0 / ts, w1 = r1 / ts;

        int p0 = atomicAdd(&counts[i0], 1);
        lists[i0 * T_TOK + p0] = (tok << 1);
        wlist[i0 * T_TOK + p0] = w0;
        int p1 = atomicAdd(&counts[i1], 1);
        lists[i1 * T_TOK + p1] = (tok << 1) | 1;
        wlist[i1 * T_TOK + p1] = w1;
    }
}

// ---------------- fp32 -> bf16 bulk conversion (memory-bound) ----------------
__device__ __forceinline__ bf16x8 cvt8(const float* __restrict__ s) {
    const f32x4 v0 = __builtin_nontemporal_load(reinterpret_cast<const f32x4*>(s));
    const f32x4 v1 = __builtin_nontemporal_load(reinterpret_cast<const f32x4*>(s + 4));
    bf16x8 h;
    h[0] = (__bf16)v0[0]; h[1] = (__bf16)v0[1]; h[2] = (__bf16)v0[2]; h[3] = (__bf16)v0[3];
    h[4] = (__bf16)v1[0]; h[5] = (__bf16)v1[1]; h[6] = (__bf16)v1[2]; h[7] = (__bf16)v1[3];
    return h;
}

__global__ __launch_bounds__(256)
void k_cvt_bf16(const float* __restrict__ src, __bf16* __restrict__ dst, long n8) {
    long i = (long)blockIdx.x * blockDim.x + threadIdx.x;
    const long stride = (long)gridDim.x * blockDim.x;
    for (; i < n8; i += stride)
        *reinterpret_cast<bf16x8*>(dst + i * 8) = cvt8(src + i * 8);
}

// one launch for the three weight tensors (equal sizes)
__global__ __launch_bounds__(256)
void k_cvt3_bf16(const float* __restrict__ s0, const float* __restrict__ s1, const float* __restrict__ s2,
                 __bf16* __restrict__ d0, __bf16* __restrict__ d1, __bf16* __restrict__ d2, long n8each) {
    long i = (long)blockIdx.x * blockDim.x + threadIdx.x;
    const long stride = (long)gridDim.x * blockDim.x;
    const long n2 = 2 * n8each, n3 = 3 * n8each;
    for (; i < n3; i += stride) {
        const float* src; __bf16* dst; long off;
        if (i < n8each)      { src = s0; dst = d0; off = i; }
        else if (i < n2)     { src = s1; dst = d1; off = i - n8each; }
        else                 { src = s2; dst = d2; off = i - n2; }
        *reinterpret_cast<bf16x8*>(dst + off * 8) = cvt8(src + off * 8);
    }
}

// ---------------- helpers ----------------
__device__ __forceinline__ void cvt_store8(void* lds_base, int woff, const float* __restrict__ src) {
    const f32x4 v0 = *reinterpret_cast<const f32x4*>(src);
    const f32x4 v1 = *reinterpret_cast<const f32x4*>(src + 4);
    bf16x8 h;
    h[0] = (__bf16)v0[0]; h[1] = (__bf16)v0[1]; h[2] = (__bf16)v0[2]; h[3] = (__bf16)v0[3];
    h[4] = (__bf16)v1[0]; h[5] = (__bf16)v1[1]; h[6] = (__bf16)v1[2]; h[7] = (__bf16)v1[3];
    *reinterpret_cast<bf16x8*>(reinterpret_cast<char*>(lds_base) + woff) = h;
}

__device__ __forceinline__ bf16x8 lds_frag(const void* lds_base, int row, int klo) {
    int off = (row * 128 + klo) ^ ((row & 7) << 4);
    return *reinterpret_cast<const bf16x8*>(reinterpret_cast<const char*>(lds_base) + off);
}

// async 16B global->LDS; LDS dest is wave-uniform base + lane*16 (m104)
__device__ __forceinline__ void gload16(const void* g, void* l) {
    __builtin_amdgcn_global_load_lds(
        (const __attribute__((address_space(1))) unsigned int*)g,
        (__attribute__((address_space(3))) unsigned int*)l,
        16, 0, 0);
}

// ---- fragment sets (register double-buffer across kk phases) ----
struct FragsA { bf16x8 a[4]; bf16x8 b1[2]; bf16x8 b3[2]; };
struct FragsB { bf16x8 a[4]; bf16x8 b[4]; };

__device__ __forceinline__ void read_fragsA(FragsA& f, const __bf16* bx, const __bf16* w1s, const __bf16* w3s,
                                            int wm, int wn, int lane, int klo) {
    #pragma unroll
    for (int m = 0; m < 4; ++m)
        f.a[m] = lds_frag(bx, wm + m * 16 + (lane & 15), klo);
    #pragma unroll
    for (int n = 0; n < 2; ++n) {
        const int r = wn + n * 16 + (lane & 15);
        f.b1[n] = lds_frag(w1s, r, klo);
        f.b3[n] = lds_frag(w3s, r, klo);
    }
}

__device__ __forceinline__ void mfmaA(f32x4 (&accg)[4][2], f32x4 (&accu)[4][2], const FragsA& f) {
    __builtin_amdgcn_s_setprio(1);
    #pragma unroll
    for (int m = 0; m < 4; ++m)
        #pragma unroll
        for (int n = 0; n < 2; ++n) {
            accg[m][n] = __builtin_amdgcn_mfma_f32_16x16x32_bf16(f.a[m], f.b1[n], accg[m][n], 0, 0, 0);
            accu[m][n] = __builtin_amdgcn_mfma_f32_16x16x32_bf16(f.a[m], f.b3[n], accu[m][n], 0, 0, 0);
        }
    __builtin_amdgcn_s_setprio(0);
}

__device__ __forceinline__ void read_fragsB(FragsB& f, const __bf16* bh, const __bf16* bw,
                                            int wm, int wn, int lane, int klo) {
    #pragma unroll
    for (int m = 0; m < 4; ++m)
        f.a[m] = lds_frag(bh, wm + m * 16 + (lane & 15), klo);
    #pragma unroll
    for (int n = 0; n < 4; ++n)
        f.b[n] = lds_frag(bw, wn + n * 16 + (lane & 15), klo);
}

__device__ __forceinline__ void mfmaB(f32x4 (&acc)[4][4], const FragsB& f) {
    __builtin_amdgcn_s_setprio(1);
    #pragma unroll
    for (int m = 0; m < 4; ++m)
        #pragma unroll
        for (int n = 0; n < 4; ++n)
            acc[m][n] = __builtin_amdgcn_mfma_f32_16x16x32_bf16(f.a[m], f.b[n], acc[m][n], 0, 0, 0);
    __builtin_amdgcn_s_setprio(0);
}

// ================= FAST PATH (bf16 sources, reg-pipelined K-step) =================

// Pass A: h = silu(x@w1^T) * (x@w3^T). 512 thr, tile 128x128, BK=64, 3-buf LDS (144KB).
// Single barrier/K-step: lgkmcnt(0) at the wait guarantees all reads of the stage target drained.
__global__ __launch_bounds__(512, 2)
void k_gateup_b16(const __bf16* __restrict__ xb, const __bf16* __restrict__ w1b,
                  const __bf16* __restrict__ w3b,
                  const int* __restrict__ counts, const int* __restrict__ lists,
                  __bf16* __restrict__ hbuf) {
    const int e   = blockIdx.z;
    const int cnt = counts[e];
    const int mt  = blockIdx.y;
    if (mt * 128 >= cnt) return;
    const int nt  = blockIdx.x;

    __shared__ __align__(16) __bf16 sX [3][8192];
    __shared__ __align__(16) __bf16 sW1[3][8192];
    __shared__ __align__(16) __bf16 sW3[3][8192];

    const int t    = threadIdx.x;
    const int lane = t & 63;
    const int wave = t >> 6;             // 0..7
    const int wm   = (wave >> 2) * 64;   // 0,64
    const int wn   = (wave & 3) * 32;    // 0,32,64,96

    // staging: tile 16KB = 16 chunks of 1024B; wave owns chunks w and w+8.
    // chunk c covers rows 8c..8c+7; lane l -> row 8c+(l>>3), k-granule ((l&7)^(l>>3))*8
    // == inverse of read swizzle byte ^= ((row&7)<<4).
    const int lrow = lane >> 3;
    const int kel  = ((lane & 7) ^ lrow) * 8;

    const __bf16* gX[2]; const __bf16* g1[2]; const __bf16* g3[2];
    int ldo[2];
    #pragma unroll
    for (int cq = 0; cq < 2; ++cq) {
        const int c   = wave + cq * 8;
        const int row = c * 8 + lrow;
        int mi  = mt * 128 + row;
        int mic = mi < cnt - 1 ? mi : cnt - 1;
        int tok = lists[e * T_TOK + mic] >> 1;
        gX[cq] = xb + (size_t)tok * HD + kel;
        const int grow = nt * 128 + row;
        g1[cq] = w1b + ((size_t)e * ID + grow) * HD + kel;
        g3[cq] = w3b + ((size_t)e * ID + grow) * HD + kel;
        ldo[cq] = c * 1024;
    }

    f32x4 accg[4][2] = {};
    f32x4 accu[4][2] = {};

#define STAGE_A(b, kt) do { \
    _Pragma("unroll") \
    for (int cq = 0; cq < 2; ++cq) { \
        gload16(gX[cq] + (kt), (char*)sX [b] + ldo[cq]); \
        gload16(g1[cq] + (kt), (char*)sW1[b] + ldo[cq]); \
        gload16(g3[cq] + (kt), (char*)sW3[b] + ldo[cq]); \
    } } while (0)

    const int klo0 = (lane >> 4) << 4;   // byte offset of lane's 8-bf16 chunk, kk=0
    const int klo1 = 64 + klo0;          // kk=1

    const int NT = HD / 64;   // 32
    STAGE_A(0, 0);
    STAGE_A(1, 64);
    asm volatile("s_waitcnt vmcnt(6) lgkmcnt(0)" ::: "memory");   // tile0 landed; tile1 in flight
    __builtin_amdgcn_s_barrier();
    __builtin_amdgcn_sched_barrier(0);

    FragsA fc, fn;
    read_fragsA(fc, sX[0], sW1[0], sW3[0], wm, wn, lane, klo0);

    for (int it = 0; it < NT - 2; ++it) {
        const int bc = it % 3, bn2 = (it + 1) % 3, bs = (it + 2) % 3;
        read_fragsA(fn, sX[bc], sW1[bc], sW3[bc], wm, wn, lane, klo1);  // kk1(t), hides under MFMA kk0
        STAGE_A(bs, (it + 2) * 64);
        mfmaA(accg, accu, fc);                                          // kk0(t)
        // lgkmcnt(0): all waves' LDS reads (incl. fn of this iter) drained before the barrier,
        // so next iteration's STAGE into (it+3)%3 cannot race any read. vmcnt(6): tile t+1 landed.
        asm volatile("s_waitcnt vmcnt(6) lgkmcnt(0)" ::: "memory");
        __builtin_amdgcn_s_barrier();
        __builtin_amdgcn_sched_barrier(0);
        read_fragsA(fc, sX[bn2], sW1[bn2], sW3[bn2], wm, wn, lane, klo0); // kk0(t+1), hides under MFMA kk1
        mfmaA(accg, accu, fn);                                          // kk1(t)
    }
    {   // it = NT-2: no new STAGE; drain tile NT-1
        const int bc = (NT - 2) % 3, bn2 = (NT - 1) % 3;
        read_fragsA(fn, sX[bc], sW1[bc], sW3[bc], wm, wn, lane, klo1);
        mfmaA(accg, accu, fc);
        asm volatile("s_waitcnt vmcnt(0) lgkmcnt(0)" ::: "memory");
        __builtin_amdgcn_s_barrier();
        __builtin_amdgcn_sched_barrier(0);
        read_fragsA(fc, sX[bn2], sW1[bn2], sW3[bn2], wm, wn, lane, klo0);
        mfmaA(accg, accu, fn);
    }
    {   // it = NT-1
        const int bc = (NT - 1) % 3;
        read_fragsA(fn, sX[bc], sW1[bc], sW3[bc], wm, wn, lane, klo1);
        mfmaA(accg, accu, fc);
        mfmaA(accg, accu, fn);
    }
#undef STAGE_A

    // SwiGLU epilogue -> hbuf[slot][i] (bf16)
    const int col_l = lane & 15;
    const int row_l = (lane >> 4) * 4;
    #pragma unroll
    for (int m = 0; m < 4; ++m) {
        #pragma unroll
        for (int j = 0; j < 4; ++j) {
            int tl = wm + m * 16 + row_l + j;
            int mi = mt * 128 + tl;
            if (mi < cnt) {
                int slot = lists[e * T_TOK + mi];
                __bf16* hrow = hbuf + (size_t)slot * ID + nt * 128 + wn;
                #pragma unroll
                for (int n = 0; n < 2; ++n) {
                    float g = accg[m][n][j];
                    float u = accu[m][n][j];
                    float hv = (g / (1.0f + expf(-g))) * u;
                    hrow[n * 16 + col_l] = (__bf16)hv;
                }
            }
        }
    }
}

// Pass B: out[tok] += w * (h @ w2^T). 512 thr, tile 256(M)x128(N), BK=64, 3-buf LDS (144KB).
// Per-wave 64x64 output: MFMA:LDS-read = 16:8 per kk (2x the old 64x32 shape).
__global__ __launch_bounds__(512, 2)
void k_down_b16(const __bf16* __restrict__ hbuf, const __bf16* __restrict__ w2b,
                const int* __restrict__ counts, const int* __restrict__ lists,
                const float* __restrict__ wlist, float* __restrict__ out) {
    const int e   = blockIdx.z;
    const int cnt = counts[e];
    const int mt  = blockIdx.y;
    if (mt * 256 >= cnt) return;
    const int nt  = blockIdx.x;

    __shared__ __align__(16) __bf16 sH[3][256 * 64];   // 3 x 32KB
    __shared__ __align__(16) __bf16 sW[3][128 * 64];   // 3 x 16KB -> 144KB

    const int t    = threadIdx.x;
    const int lane = t & 63;
    const int wave = t >> 6;             // 0..7
    const int wm   = (wave >> 1) * 64;   // 0,64,128,192
    const int wn   = (wave & 1) * 64;    // 0,64

    const int lrow = lane >> 3;
    const int kel  = ((lane & 7) ^ lrow) * 8;

    // H-tile: 256 rows = 32 chunks of 1024B, 4 per wave. W-tile: 128 rows = 16 chunks, 2 per wave.
    const __bf16* gH[4]; int loH[4];
    #pragma unroll
    for (int q = 0; q < 4; ++q) {
        const int c   = wave + q * 8;          // 0..31
        const int row = c * 8 + lrow;          // 0..255
        int mi  = mt * 256 + row;
        int mic = mi < cnt - 1 ? mi : cnt - 1;
        int slot = lists[e * T_TOK + mic];
        gH[q]  = hbuf + (size_t)slot * ID + kel;
        loH[q] = c * 1024;
    }
    const __bf16* gW[2]; int loW[2];
    #pragma unroll
    for (int q = 0; q < 2; ++q) {
        const int c   = wave + q * 8;          // 0..15
        const int row = c * 8 + lrow;          // 0..127
        const int grow = nt * 128 + row;
        gW[q]  = w2b + ((size_t)e * HD + grow) * ID + kel;
        loW[q] = c * 1024;
    }

    f32x4 acc[4][4] = {};

#define STAGE_B(b, kt) do { \
    _Pragma("unroll") \
    for (int q = 0; q < 4; ++q) gload16(gH[q] + (kt), (char*)sH[b] + loH[q]); \
    _Pragma("unroll") \
    for (int q = 0; q < 2; ++q) gload16(gW[q] + (kt), (char*)sW[b] + loW[q]); \
    } while (0)

    const int klo0 = (lane >> 4) << 4;
    const int klo1 = 64 + klo0;

    const int NT = ID / 64;   // 88
    STAGE_B(0, 0);
    STAGE_B(1, 64);
    asm volatile("s_waitcnt vmcnt(6) lgkmcnt(0)" ::: "memory");
    __builtin_amdgcn_s_barrier();
    __builtin_amdgcn_sched_barrier(0);

    FragsB fc, fn;
    read_fragsB(fc, sH[0], sW[0], wm, wn, lane, klo0);

    for (int it = 0; it < NT - 2; ++it) {
        const int bc = it % 3, bn2 = (it + 1) % 3, bs = (it + 2) % 3;
        read_fragsB(fn, sH[bc], sW[bc], wm, wn, lane, klo1);
        STAGE_B(bs, (it + 2) * 64);
        mfmaB(acc, fc);
        asm volatile("s_waitcnt vmcnt(6) lgkmcnt(0)" ::: "memory");
        __builtin_amdgcn_s_barrier();
        __builtin_amdgcn_sched_barrier(0);
        read_fragsB(fc, sH[bn2], sW[bn2], wm, wn, lane, klo0);
        mfmaB(acc, fn);
    }
    {   // it = NT-2
        const int bc = (NT - 2) % 3, bn2 = (NT - 1) % 3;
        read_fragsB(fn, sH[bc], sW[bc], wm, wn, lane, klo1);
        mfmaB(acc, fc);
        asm volatile("s_waitcnt vmcnt(0) lgkmcnt(0)" ::: "memory");
        __builtin_amdgcn_s_barrier();
        __builtin_amdgcn_sched_barrier(0);
        read_fragsB(fc, sH[bn2], sW[bn2], wm, wn, lane, klo0);
        mfmaB(acc, fn);
    }
    {   // it = NT-1
        const int bc = (NT - 1) % 3;
        read_fragsB(fn, sH[bc], sW[bc], wm, wn, lane, klo1);
        mfmaB(acc, fc);
        mfmaB(acc, fn);
    }
#undef STAGE_B

    // weighted scatter-add: exactly 2 atomic contributions per out element
    const int col_l = lane & 15;
    const int row_l = (lane >> 4) * 4;
    #pragma unroll
    for (int m = 0; m < 4; ++m) {
        #pragma unroll
        for (int j = 0; j < 4; ++j) {
            int tl = wm + m * 16 + row_l + j;
            int mi = mt * 256 + tl;
            if (mi < cnt) {
                int slot = lists[e * T_TOK + mi];
                int tok  = slot >> 1;
                float w  = wlist[e * T_TOK + mi];
                float* orow = out + (size_t)tok * HD + nt * 128 + wn;
                #pragma unroll
                for (int n = 0; n < 4; ++n)
                    atomicAdd(&orow[n * 16 + col_l], w * acc[m][n][j]);
            }
        }
    }
}

// ================= FALLBACK PATH (fp32 sources, reg-staged; round-1 proven) =================

__global__ __launch_bounds__(256)
void k_gateup_f32(const float* __restrict__ x, const float* __restrict__ w1,
                  const float* __restrict__ w3,
                  const int* __restrict__ counts, const int* __restrict__ lists,
                  __bf16* __restrict__ hbuf) {
    const int e   = blockIdx.z;
    const int cnt = counts[e];
    const int mt  = blockIdx.y;
    if (mt * 128 >= cnt) return;
    const int nt  = blockIdx.x;

    __shared__ __align__(16) __bf16 sX [128 * 64];
    __shared__ __align__(16) __bf16 sW1[128 * 64];
    __shared__ __align__(16) __bf16 sW3[128 * 64];

    const int t    = threadIdx.x;
    const int lane = t & 63;
    const int wave = t >> 6;
    const int wm   = (wave >> 1) * 64;
    const int wn   = (wave & 1) * 64;
    const int cc = t & 7;
    const int r0 = t >> 3;

    const float* srcX[4]; const float* src1[4]; const float* src3[4];
    int woff[4];
    #pragma unroll
    for (int q = 0; q < 4; ++q) {
        int row = r0 + 32 * q;
        int mi  = mt * 128 + row;
        int mic = mi < cnt - 1 ? mi : cnt - 1;
        int slot = lists[e * T_TOK + mic];
        int tok  = slot >> 1;
        srcX[q] = x + (size_t)tok * HD + cc * 8;
        int grow = nt * 128 + row;
        src1[q] = w1 + ((size_t)e * ID + grow) * HD + cc * 8;
        src3[q] = w3 + ((size_t)e * ID + grow) * HD + cc * 8;
        woff[q] = (row * 128 + cc * 16) ^ ((row & 7) << 4);
    }

    f32x4 accg[4][4] = {};
    f32x4 accu[4][4] = {};

    for (int kt = 0; kt < HD; kt += 64) {
        __syncthreads();
        #pragma unroll
        for (int q = 0; q < 4; ++q) {
            cvt_store8(sX,  woff[q], srcX[q] + kt);
            cvt_store8(sW1, woff[q], src1[q] + kt);
            cvt_store8(sW3, woff[q], src3[q] + kt);
        }
        __syncthreads();
        #pragma unroll
        for (int kk = 0; kk < 2; ++kk) {
            const int klo = kk * 64 + ((lane >> 4) << 4);
            bf16x8 af[4], b1f[4], b3f[4];
            #pragma unroll
            for (int m = 0; m < 4; ++m)
                af[m] = lds_frag(sX, wm + m * 16 + (lane & 15), klo);
            #pragma unroll
            for (int n = 0; n < 4; ++n) {
                int row = wn + n * 16 + (lane & 15);
                b1f[n] = lds_frag(sW1, row, klo);
                b3f[n] = lds_frag(sW3, row, klo);
            }
            #pragma unroll
            for (int m = 0; m < 4; ++m)
                #pragma unroll
                for (int n = 0; n < 4; ++n) {
                    accg[m][n] = __builtin_amdgcn_mfma_f32_16x16x32_bf16(af[m], b1f[n], accg[m][n], 0, 0, 0);
                    accu[m][n] = __builtin_amdgcn_mfma_f32_16x16x32_bf16(af[m], b3f[n], accu[m][n], 0, 0, 0);
                }
        }
    }

    const int col_l = lane & 15;
    const int row_l = (lane >> 4) * 4;
    #pragma unroll
    for (int m = 0; m < 4; ++m) {
        #pragma unroll
        for (int j = 0; j < 4; ++j) {
            int tl = wm + m * 16 + row_l + j;
            int mi = mt * 128 + tl;
            if (mi < cnt) {
                int slot = lists[e * T_TOK + mi];
                __bf16* hrow = hbuf + (size_t)slot * ID + nt * 128 + wn;
                #pragma unroll
                for (int n = 0; n < 4; ++n) {
                    float g = accg[m][n][j];
                    float u = accu[m][n][j];
                    float hv = (g / (1.0f + expf(-g))) * u;
                    hrow[n * 16 + col_l] = (__bf16)hv;
                }
            }
        }
    }
}

__global__ __launch_bounds__(256)
void k_down_f32(const __bf16* __restrict__ hbuf, const float* __restrict__ w2,
                const int* __restrict__ counts, const int* __restrict__ lists,
                const float* __restrict__ wlist, float* __restrict__ out) {
    const int e   = blockIdx.z;
    const int cnt = counts[e];
    const int mt  = blockIdx.y;
    if (mt * 128 >= cnt) return;
    const int nt  = blockIdx.x;

    __shared__ __align__(16) __bf16 sH[128 * 64];
    __shared__ __align__(16) __bf16 sW[128 * 64];

    const int t    = threadIdx.x;
    const int lane = t & 63;
    const int wave = t >> 6;
    const int wm   = (wave >> 1) * 64;
    const int wn   = (wave & 1) * 64;
    const int cc = t & 7;
    const int r0 = t >> 3;

    const __bf16* srcH[4]; const float* srcW[4];
    int woff[4];
    #pragma unroll
    for (int q = 0; q < 4; ++q) {
        int row = r0 + 32 * q;
        int mi  = mt * 128 + row;
        int mic = mi < cnt - 1 ? mi : cnt - 1;
        int slot = lists[e * T_TOK + mic];
        srcH[q] = hbuf + (size_t)slot * ID + cc * 8;
        int grow = nt * 128 + row;
        srcW[q] = w2 + ((size_t)e * HD + grow) * ID + cc * 8;
        woff[q] = (row * 128 + cc * 16) ^ ((row & 7) << 4);
    }

    f32x4 acc[4][4] = {};

    for (int kt = 0; kt < ID; kt += 64) {
        __syncthreads();
        #pragma unroll
        for (int q = 0; q < 4; ++q) {
            bf16x8 v = *reinterpret_cast<const bf16x8*>(srcH[q] + kt);
            *reinterpret_cast<bf16x8*>(reinterpret_cast<char*>(sH) + woff[q]) = v;
            cvt_store8(sW, woff[q], srcW[q] + kt);
        }
        __syncthreads();
        #pragma unroll
        for (int kk = 0; kk < 2; ++kk) {
            const int klo = kk * 64 + ((lane >> 4) << 4);
            bf16x8 af[4], bf[4];
            #pragma unroll
            for (int m = 0; m < 4; ++m)
                af[m] = lds_frag(sH, wm + m * 16 + (lane & 15), klo);
            #pragma unroll
            for (int n = 0; n < 4; ++n)
                bf[n] = lds_frag(sW, wn + n * 16 + (lane & 15), klo);
            #pragma unroll
            for (int m = 0; m < 4; ++m)
                #pragma unroll
                for (int n = 0; n < 4; ++n)
                    acc[m][n] = __builtin_amdgcn_mfma_f32_16x16x32_bf16(af[m], bf[n], acc[m][n], 0, 0, 0);
        }
    }

    const int col_l = lane & 15;
    const int row_l = (lane >> 4) * 4;
    #pragma unroll
    for (int m = 0; m < 4; ++m) {
        #pragma unroll
        for (int j = 0; j < 4; ++j) {
            int tl = wm + m * 16 + row_l + j;
            int mi = mt * 128 + tl;
            if (mi < cnt) {
                int slot = lists[e * T_TOK + mi];
                int tok  = slot >> 1;
                float w  = wlist[e * T_TOK + mi];
                float* orow = out + (size_t)tok * HD + nt * 128 + wn;
                #pragma unroll
                for (int n = 0; n < 4; ++n)
                    atomicAdd(&orow[n * 16 + col_l], w * acc[m][n][j]);
            }
        }
    }
}

extern "C" void kernel_launch(void* const* d_in, const int* in_sizes, int n_in,
                              void* d_out, int out_size, void* d_ws, size_t ws_size,
                              hipStream_t stream) {
    const float* x  = (const float*)d_in[0];
    const float* wg = (const float*)d_in[1];
    const float* w1 = (const float*)d_in[2];
    const float* w2 = (const float*)d_in[3];
    const float* w3 = (const float*)d_in[4];
    float* out = (float*)d_out;

    const size_t HBUF_B = (size_t)2 * T_TOK * ID * 2;      // 184,549,376
    const size_t XB_B   = (size_t)T_TOK * HD * 2;          //  33,554,432
    const size_t WB_B   = (size_t)NE * ID * HD * 2;        // 184,549,376 each
    const size_t SMALL  = 4608 + 512 + (size_t)NE * T_TOK * 4 * 2 + 4096;

    char* ws = (char*)d_ws;
    __bf16* hbuf = (__bf16*)ws;

    const size_t XB_OFF  = HBUF_B;
    const size_t W1_OFF  = XB_OFF + XB_B;
    const size_t W3_OFF  = W1_OFF + WB_B;
    const size_t W2_OFF  = W3_OFF + WB_B;
    const size_t TAIL    = W2_OFF + WB_B;
    const size_t NEED_FULL = TAIL + SMALL;
    const size_t NEED_MIN  = HBUF_B + SMALL;

    if (ws_size >= NEED_FULL) {
        __bf16* xb  = (__bf16*)(ws + XB_OFF);
        __bf16* w1b = (__bf16*)(ws + W1_OFF);
        __bf16* w3b = (__bf16*)(ws + W3_OFF);
        __bf16* w2b = (__bf16*)(ws + W2_OFF);
        int*   lut    = (int*)(ws + TAIL);
        int*   counts = (int*)(ws + TAIL + 4608);
        int*   lists  = (int*)(ws + TAIL + 4608 + 512);
        float* wlist  = (float*)(ws + TAIL + 4608 + 512 + (size_t)NE * T_TOK * 4);

        (void)hipMemsetAsync(out, 0, (size_t)out_size * sizeof(float), stream);
        (void)hipMemsetAsync(counts, 0, 64, stream);
        k_build_lut<<<dim3(5), dim3(256), 0, stream>>>(lut);
        k_router<<<dim3(T_TOK), dim3(64), 0, stream>>>(x, wg, lut, counts, lists, wlist);
        k_cvt_bf16<<<dim3(1024), dim3(256), 0, stream>>>(x, xb, (long)T_TOK * HD / 8);
        k_cvt3_bf16<<<dim3(4096), dim3(256), 0, stream>>>(w1, w3, w2, w1b, w3b, w2b, (long)NE * ID * HD / 8);
        k_gateup_b16<<<dim3(ID / 128, T_TOK / 128, NE), dim3(512), 0, stream>>>(xb, w1b, w3b, counts, lists, hbuf);
        k_down_b16<<<dim3(HD / 128, T_TOK / 256, NE), dim3(512), 0, stream>>>(hbuf, w2b, counts, lists, wlist, out);
    } else if (ws_size >= NEED_MIN) {
        int*   lut    = (int*)(ws + HBUF_B);
        int*   counts = (int*)(ws + HBUF_B + 4608);
        int*   lists  = (int*)(ws + HBUF_B + 4608 + 512);
        float* wlist  = (float*)(ws + HBUF_B + 4608 + 512 + (size_t)NE * T_TOK * 4);

        (void)hipMemsetAsync(out, 0, (size_t)out_size * sizeof(float), stream);
        (void)hipMemsetAsync(counts, 0, 64, stream);
        k_build_lut<<<dim3(5), dim3(256), 0, stream>>>(lut);
        k_router<<<dim3(T_TOK), dim3(64), 0, stream>>>(x, wg, lut, counts, lists, wlist);
        k_gateup_f32<<<dim3(ID / 128, T_TOK / 128, NE), dim3(256), 0, stream>>>(x, w1, w3, counts, lists, hbuf);
        k_down_f32<<<dim3(HD / 128, T_TOK / 128, NE), dim3(256), 0, stream>>>(hbuf, w2, counts, lists, wlist, out);
    } else {
        (void)hipMemsetAsync(d_out, 0x7F, (size_t)out_size * sizeof(float), stream);
    }
}